// Round 2
// baseline (126.353 us; speedup 1.0000x reference)
//
#include <hip/hip_runtime.h>

// EMA1D straight-through: forward value is exactly x (state - state == 0),
// so this is a pure 256 MiB -> 256 MiB streaming copy. HBM-bound.
// R1: 1 load in flight/wave -> 4.79 TB/s. R2: batch 4 independent loads
// + nontemporal hints (streaming data, no reuse) to approach ~6.3 TB/s.

typedef float f32x4 __attribute__((ext_vector_type(4)));

__global__ __launch_bounds__(256) void ema1d_copy_kernel(
    const f32x4* __restrict__ in, f32x4* __restrict__ out, long n4) {
    long tid = (long)blockIdx.x * blockDim.x + threadIdx.x;
    long stride = (long)gridDim.x * blockDim.x;

    long i = tid;
    // Main loop: 4 independent loads issued back-to-back, then 4 stores.
    for (; i + 3 * stride < n4; i += 4 * stride) {
        f32x4 a = __builtin_nontemporal_load(in + i);
        f32x4 b = __builtin_nontemporal_load(in + i + stride);
        f32x4 c = __builtin_nontemporal_load(in + i + 2 * stride);
        f32x4 d = __builtin_nontemporal_load(in + i + 3 * stride);
        __builtin_nontemporal_store(a, out + i);
        __builtin_nontemporal_store(b, out + i + stride);
        __builtin_nontemporal_store(c, out + i + 2 * stride);
        __builtin_nontemporal_store(d, out + i + 3 * stride);
    }
    // Tail (not taken for 64*128*8192 with grid 2048x256, kept for safety).
    for (; i < n4; i += stride) {
        f32x4 v = __builtin_nontemporal_load(in + i);
        __builtin_nontemporal_store(v, out + i);
    }
}

extern "C" void kernel_launch(void* const* d_in, const int* in_sizes, int n_in,
                              void* d_out, int out_size, void* d_ws, size_t ws_size,
                              hipStream_t stream) {
    const float* x = (const float*)d_in[0];
    float* out = (float*)d_out;

    long n = (long)out_size;   // 67,108,864 elements, divisible by 4
    long n4 = n / 4;

    int block = 256;
    long want = (n4 + block - 1) / block;
    int grid = (int)(want < 2048 ? want : 2048);  // 8 blocks/CU x 256 CUs

    ema1d_copy_kernel<<<grid, block, 0, stream>>>(
        (const f32x4*)x, (f32x4*)out, n4);
}

// Round 3
// 98.872 us; speedup vs baseline: 1.2779x; 1.2779x over previous
//
#include <hip/hip_runtime.h>

// EMA1D straight-through: forward value is exactly x, so this is a pure
// 256 MiB -> 256 MiB streaming copy. HBM-bound.
// R1 (1 load in flight/wave): 112 us = 4.79 TB/s.
// R2 (4 loads in flight, 8 MiB apart + nt): 126 us — REGRESSION. The 8 MiB
//    power-of-2 stride between in-flight loads aliased HBM channels.
// R3: 4 loads in flight per wave, only 4 KiB apart (contiguous 16 KiB
//    block-chunks), no nt. MLP without channel aliasing.

typedef float f32x4 __attribute__((ext_vector_type(4)));

#define BLOCK 256
#define UNROLL 4
#define CHUNK (BLOCK * UNROLL)   // 1024 float4 = 16 KiB per block-iteration

__global__ __launch_bounds__(BLOCK) void ema1d_copy_kernel(
    const f32x4* __restrict__ in, f32x4* __restrict__ out, long n4) {
    long t = threadIdx.x;
    long chunk_stride = (long)gridDim.x * CHUNK;
    long base = (long)blockIdx.x * CHUNK;

    // Main loop: full chunks. 4 independent loads per wave, 4 KiB apart.
    for (; base + CHUNK <= n4; base += chunk_stride) {
        f32x4 a = in[base + t];
        f32x4 b = in[base + t + BLOCK];
        f32x4 c = in[base + t + 2 * BLOCK];
        f32x4 d = in[base + t + 3 * BLOCK];
        out[base + t]             = a;
        out[base + t + BLOCK]     = b;
        out[base + t + 2 * BLOCK] = c;
        out[base + t + 3 * BLOCK] = d;
    }
    // Tail (not taken for this shape; kept for safety).
    for (long i = base + t; i < n4; i += BLOCK) {
        out[i] = in[i];
    }
}

extern "C" void kernel_launch(void* const* d_in, const int* in_sizes, int n_in,
                              void* d_out, int out_size, void* d_ws, size_t ws_size,
                              hipStream_t stream) {
    const float* x = (const float*)d_in[0];
    float* out = (float*)d_out;

    long n = (long)out_size;   // 67,108,864 elements, divisible by 4
    long n4 = n / 4;           // 16,777,216 float4

    int grid = 2048;           // 8 blocks/CU x 256 CUs; 8 chunk-iters/block

    ema1d_copy_kernel<<<grid, BLOCK, 0, stream>>>(
        (const f32x4*)x, (f32x4*)out, n4);
}